// Round 6
// baseline (306.573 us; speedup 1.0000x reference)
//
#include <hip/hip_runtime.h>

#define N_NODES 20000
#define N_EDGES 320000
#define DIM 128
#define NLAYER 3
#define SCAN_BLK 1024
#define N_SCAN_BLKS ((N_NODES + SCAN_BLK - 1) / SCAN_BLK)  // 20
#define LDS_STRIDE 136

// prep kernel task ranges (256-thread blocks)
#define PREP_CASTX_BLKS 2500
#define PREP_CASTW_BLKS 208
#define PREP_ZERO_BLKS 79
#define PREP_TOTAL (PREP_CASTX_BLKS + PREP_CASTW_BLKS + PREP_ZERO_BLKS)

typedef __attribute__((ext_vector_type(8))) short short8;
typedef __attribute__((ext_vector_type(4))) float f32x4;

__device__ inline ushort f2bf(float f) {
  uint u = __float_as_uint(f);
  uint r = (u + 0x7fffu + ((u >> 16) & 1u)) >> 16;
  return (ushort)r;
}
__device__ inline float bf2f(ushort u) { return __uint_as_float(((uint)u) << 16); }

// ---------------- fused prep: cast_x | cast_w | zero degc ----------------
__global__ __launch_bounds__(256) void prep_kernel(
    const float* __restrict__ x, ushort* __restrict__ xb,
    const float* __restrict__ Wq, const float* __restrict__ Wk,
    const float* __restrict__ Wv, const float* __restrict__ Ws,
    const float* __restrict__ Wo, ushort* __restrict__ wt,
    int* __restrict__ degc) {
  int b = blockIdx.x;
  int t = threadIdx.x;
  if (b < PREP_CASTX_BLKS) {
    int i = b * 256 + t;
    float4 f = ((const float4*)x)[i];
    ushort4 o;
    o.x = f2bf(f.x); o.y = f2bf(f.y); o.z = f2bf(f.z); o.w = f2bf(f.w);
    ((ushort4*)xb)[i] = o;
  } else if (b < PREP_CASTX_BLKS + PREP_CASTW_BLKS) {
    int idx = b - PREP_CASTX_BLKS;
    int z = idx >> 4;
    int r = idx & 15;
    int k0 = (r >> 2) * 32, n0 = (r & 3) * 32;
    const float* src;
    if (z < 12) {
      int l = z >> 2, j = z & 3;
      src = (j == 0 ? Wq : j == 1 ? Wk : j == 2 ? Wv : Ws) + (size_t)l * DIM * DIM;
    } else {
      src = Wo;
    }
    __shared__ float tile[32][33];
    int tx = t & 31, ty = t >> 5;
    #pragma unroll
    for (int i = 0; i < 32; i += 8)
      tile[ty + i][tx] = src[(size_t)(k0 + ty + i) * DIM + n0 + tx];
    __syncthreads();
    ushort* dst = wt + (size_t)z * DIM * DIM;
    #pragma unroll
    for (int i = 0; i < 32; i += 8)
      dst[(size_t)(n0 + ty + i) * DIM + k0 + tx] = f2bf(tile[tx][ty + i]);
  } else {
    int i = (b - PREP_CASTX_BLKS - PREP_CASTW_BLKS) * 256 + t;
    if (i < N_NODES) degc[i] = 0;
  }
}

// ---------------- CSR build ----------------

__global__ void count_deg_kernel(const int* __restrict__ ei, int* __restrict__ deg) {
  int e = blockIdx.x * 256 + threadIdx.x;
  if (e < N_EDGES) atomicAdd(&deg[ei[N_EDGES + e]], 1);
}

__global__ __launch_bounds__(SCAN_BLK) void scan1_kernel(const int* __restrict__ deg,
                                                         int* __restrict__ rowptr,
                                                         int* __restrict__ blksum) {
  __shared__ int wsum[16];
  int t = threadIdx.x, lane = t & 63, w = t >> 6;
  int i = blockIdx.x * SCAN_BLK + t;
  int val = (i < N_NODES) ? deg[i] : 0;
  int s = val;
  #pragma unroll
  for (int off = 1; off < 64; off <<= 1) {
    int u = __shfl_up(s, off);
    if (lane >= off) s += u;
  }
  if (lane == 63) wsum[w] = s;
  __syncthreads();
  if (t < 16) {
    int wv = wsum[t];
    int ss = wv;
    #pragma unroll
    for (int off = 1; off < 16; off <<= 1) {
      int u = __shfl_up(ss, off);
      if (t >= off) ss += u;
    }
    wsum[t] = ss - wv;
  }
  __syncthreads();
  int excl = wsum[w] + s - val;
  if (i < N_NODES) rowptr[i] = excl;
  if (t == SCAN_BLK - 1) blksum[blockIdx.x] = excl + val;
}

__global__ void scan2_kernel(int* __restrict__ blksum, int* __restrict__ rowptr) {
  int t = threadIdx.x;  // 64
  int val = (t < N_SCAN_BLKS) ? blksum[t] : 0;
  int s = val;
  #pragma unroll
  for (int off = 1; off < 64; off <<= 1) {
    int u = __shfl_up(s, off);
    if (t >= off) s += u;
  }
  if (t < N_SCAN_BLKS) blksum[t] = s - val;
  if (t == 63) rowptr[N_NODES] = s;
}

__global__ __launch_bounds__(SCAN_BLK) void scan3_kernel(int* __restrict__ rowptr,
                                                         const int* __restrict__ blksum,
                                                         int* __restrict__ degc) {
  int i = blockIdx.x * SCAN_BLK + threadIdx.x;
  if (i < N_NODES) {
    rowptr[i] += blksum[blockIdx.x];
    degc[i] = 0;
  }
}

__global__ void scatter_kernel(const int* __restrict__ ei, const int* __restrict__ rowptr,
                               int* __restrict__ cursor, int* __restrict__ csr_src) {
  int e = blockIdx.x * 256 + threadIdx.x;
  if (e < N_EDGES) {
    int d = ei[N_EDGES + e];
    int s = ei[e];
    int pos = atomicAdd(&cursor[d], 1);
    csr_src[rowptr[d] + pos] = s;
  }
}

// ---------------- bf16 MFMA GEMM: O_j = X @ W_j + b_j ----------------
// mode 0: row-major, stride st. mode 1: head-major k slot. mode 2: head-major v slot.
// head-major: kvh[h][node][0..15]=k-ch, [16..31]=v-ch (64B records per (node,head)).
template <int OUT_BF16>
__global__ __launch_bounds__(256) void gemm_mfma_kernel(
    const ushort* __restrict__ X, const ushort* __restrict__ WT,
    const float* __restrict__ B0, const float* __restrict__ B1,
    const float* __restrict__ B2, const float* __restrict__ B3,
    void* __restrict__ O0, void* __restrict__ O1, void* __restrict__ O2,
    void* __restrict__ O3, int m0, int m1, int m2, int m3) {
  __shared__ ushort As[128 * LDS_STRIDE];
  int mat = blockIdx.y;
  const ushort* Wt = WT + (size_t)mat * DIM * DIM;
  const float* bias;
  void* O;
  int mode;
  switch (mat) {
    case 0: bias = B0; O = O0; mode = m0; break;
    case 1: bias = B1; O = O1; mode = m1; break;
    case 2: bias = B2; O = O2; mode = m2; break;
    default: bias = B3; O = O3; mode = m3; break;
  }
  int t = threadIdx.x;
  int wid = t >> 6, lane = t & 63;
  int row0 = blockIdx.x * 128;
  int wr = wid >> 1, wc = wid & 1;
  int lr = lane & 15;
  int kc8 = (lane >> 4) * 8;

  {
    int rowi = t >> 4;
    int col = (t & 15) * 8;
    #pragma unroll
    for (int pass = 0; pass < 8; ++pass) {
      int row = pass * 16 + rowi;
      int gr = min(row0 + row, N_NODES - 1);
      short8 val = *(const short8*)(X + (size_t)gr * DIM + col);
      *(short8*)(As + row * LDS_STRIDE + col) = val;
    }
  }
  __syncthreads();

  f32x4 acc[4][4];
  #pragma unroll
  for (int i = 0; i < 4; ++i)
    #pragma unroll
    for (int j = 0; j < 4; ++j) acc[i][j] = (f32x4){0.f, 0.f, 0.f, 0.f};

  #pragma unroll
  for (int ks = 0; ks < 4; ++ks) {
    short8 b[4];
    #pragma unroll
    for (int cf = 0; cf < 4; ++cf) {
      int c = wc * 64 + cf * 16 + lr;
      b[cf] = *(const short8*)(Wt + (size_t)c * DIM + ks * 32 + kc8);
    }
    #pragma unroll
    for (int rf = 0; rf < 4; ++rf) {
      int r = wr * 64 + rf * 16 + lr;
      short8 a = *(const short8*)(As + r * LDS_STRIDE + ks * 32 + kc8);
      #pragma unroll
      for (int cf = 0; cf < 4; ++cf)
        acc[rf][cf] = __builtin_amdgcn_mfma_f32_16x16x32_bf16(a, b[cf], acc[rf][cf], 0, 0, 0);
    }
  }

  #pragma unroll
  for (int cf = 0; cf < 4; ++cf) {
    int c = wc * 64 + cf * 16 + lr;
    float bv = bias[c];
    #pragma unroll
    for (int rf = 0; rf < 4; ++rf) {
      #pragma unroll
      for (int reg = 0; reg < 4; ++reg) {
        int r = row0 + wr * 64 + rf * 16 + (lane >> 4) * 4 + reg;
        if (r < N_NODES) {
          float val = acc[rf][cf][reg] + bv;
          if (OUT_BF16) {
            ushort v16 = f2bf(val);
            if (mode == 0)
              ((ushort*)O)[(size_t)r * DIM + c] = v16;
            else
              ((ushort*)O)[(size_t)(c >> 4) * (N_NODES * 32) + (size_t)r * 32 +
                           (c & 15) + (mode == 2 ? 16 : 0)] = v16;
          } else {
            ((float*)O)[(size_t)r * DIM + c] = val;
          }
        }
      }
    }
  }
}

// ---------------- attention gather: one wave per (dst node, head) ----------------
// h = blockIdx.x & 7 -> all blocks on XCD j (round-robin heuristic) process head j,
// whose 1.28MB kv slice is L2-resident. lane = (edge e=lane>>2, quarter qq=lane&3):
// 16 edges in flight, 8B k + 8B v per lane from one 64B record.
__global__ __launch_bounds__(256) void attn_gather_kernel(
    const ushort* __restrict__ q, const ushort* __restrict__ kvh,
    const int* __restrict__ rowptr, const int* __restrict__ csr_src,
    float* __restrict__ aout) {
  int w = threadIdx.x >> 6, lane = threadIdx.x & 63;
  int h = blockIdx.x & 7;
  int n = (blockIdx.x >> 3) * 4 + w;
  int e = lane >> 2, qq = lane & 3;
  ushort4 qu = *(const ushort4*)(q + (size_t)n * DIM + h * 16 + qq * 4);
  float qf0 = bf2f(qu.x), qf1 = bf2f(qu.y), qf2 = bf2f(qu.z), qf3 = bf2f(qu.w);
  int s0 = rowptr[n];
  int deg = rowptr[n + 1] - s0;
  const ushort* bh = kvh + (size_t)h * (N_NODES * 32);
  float dsum = 0.f, va0 = 0.f, va1 = 0.f, va2 = 0.f, va3 = 0.f;
  for (int b0 = 0; b0 < deg; b0 += 16) {
    int idx = b0 + e;
    bool valid = idx < deg;
    int src = csr_src[s0 + min(idx, deg - 1)];
    const ushort* rec = bh + (size_t)src * 32 + qq * 4;
    ushort4 ku = *(const ushort4*)rec;
    ushort4 vu = *(const ushort4*)(rec + 16);
    float part = qf0 * bf2f(ku.x) + qf1 * bf2f(ku.y) + qf2 * bf2f(ku.z) + qf3 * bf2f(ku.w);
    part += __shfl_xor(part, 1);
    part += __shfl_xor(part, 2);
    float ea = __expf(part * 0.25f);
    ea = valid ? ea : 0.f;
    dsum += ea;
    va0 = fmaf(ea, bf2f(vu.x), va0);
    va1 = fmaf(ea, bf2f(vu.y), va1);
    va2 = fmaf(ea, bf2f(vu.z), va2);
    va3 = fmaf(ea, bf2f(vu.w), va3);
  }
  #pragma unroll
  for (int off = 4; off <= 32; off <<= 1) {
    dsum += __shfl_xor(dsum, off);
    va0 += __shfl_xor(va0, off);
    va1 += __shfl_xor(va1, off);
    va2 += __shfl_xor(va2, off);
    va3 += __shfl_xor(va3, off);
  }
  if (e == 0) {
    float inv = 1.f / (dsum + 1e-16f);
    float4 o = make_float4(va0 * inv, va1 * inv, va2 * inv, va3 * inv);
    *(float4*)(aout + (size_t)n * DIM + h * 16 + qq * 4) = o;
  }
}

// ---------------- epilogue: beta-skip + relu + residual + layernorm ----------------
__global__ __launch_bounds__(256) void attn_epi_kernel(
    const float* __restrict__ aout, const ushort* __restrict__ xr,
    const float* __restrict__ xres, const float* __restrict__ wbeta,
    const float* __restrict__ lng, const float* __restrict__ lnb,
    float* __restrict__ xnext, ushort* __restrict__ xnextb) {
  int w = threadIdx.x >> 6, lane = threadIdx.x & 63;
  int n = blockIdx.x * 4 + w;
  int c0 = lane * 2;
  float2 ov = *(const float2*)(aout + (size_t)n * DIM + c0);
  float o0 = ov.x, o1 = ov.y;

  ushort2 xru = *(const ushort2*)(xr + (size_t)n * DIM + c0);
  float xr0 = bf2f(xru.x), xr1 = bf2f(xru.y);
  float wa0 = wbeta[c0] + wbeta[2 * DIM + c0];
  float wa1 = wbeta[c0 + 1] + wbeta[2 * DIM + c0 + 1];
  float wb0 = wbeta[DIM + c0] - wbeta[2 * DIM + c0];
  float wb1 = wbeta[DIM + c0 + 1] - wbeta[2 * DIM + c0 + 1];
  float bs = o0 * wa0 + o1 * wa1 + xr0 * wb0 + xr1 * wb1;
  #pragma unroll
  for (int off = 1; off < 64; off <<= 1) bs += __shfl_xor(bs, off);
  float beta = 1.f / (1.f + __expf(-bs));
  float y0 = fmaxf(beta * xr0 + (1.f - beta) * o0, 0.f);
  float y1 = fmaxf(beta * xr1 + (1.f - beta) * o1, 0.f);
  float2 rv = *(const float2*)(xres + (size_t)n * DIM + c0);
  y0 += rv.x;
  y1 += rv.y;
  float s = y0 + y1;
  #pragma unroll
  for (int off = 1; off < 64; off <<= 1) s += __shfl_xor(s, off);
  float mu = s * (1.f / 128.f);
  float d0 = y0 - mu, d1 = y1 - mu;
  float vs = d0 * d0 + d1 * d1;
  #pragma unroll
  for (int off = 1; off < 64; off <<= 1) vs += __shfl_xor(vs, off);
  float rstd = rsqrtf(vs * (1.f / 128.f) + 1e-5f);
  float2 g = *(const float2*)(lng + c0);
  float2 b = *(const float2*)(lnb + c0);
  float out0 = d0 * rstd * g.x + b.x;
  float out1 = d1 * rstd * g.y + b.y;
  *(float2*)(xnext + (size_t)n * DIM + c0) = make_float2(out0, out1);
  ushort2 ob;
  ob.x = f2bf(out0);
  ob.y = f2bf(out1);
  *(ushort2*)(xnextb + (size_t)n * DIM + c0) = ob;
}

// ---------------- launch ----------------

extern "C" void kernel_launch(void* const* d_in, const int* in_sizes, int n_in,
                              void* d_out, int out_size, void* d_ws, size_t ws_size,
                              hipStream_t stream) {
  const float* x_in = (const float*)d_in[0];
  const int* ei = (const int*)d_in[1];
  const float* Wq = (const float*)d_in[2];
  const float* bq = (const float*)d_in[3];
  const float* Wk = (const float*)d_in[4];
  const float* bk = (const float*)d_in[5];
  const float* Wv = (const float*)d_in[6];
  const float* bv = (const float*)d_in[7];
  const float* Wsk = (const float*)d_in[8];
  const float* bsk = (const float*)d_in[9];
  const float* Wb = (const float*)d_in[10];
  const float* lng = (const float*)d_in[11];
  const float* lnb = (const float*)d_in[12];
  const float* Wout = (const float*)d_in[13];
  const float* bout = (const float*)d_in[14];
  float* out = (float*)d_out;

  char* p = (char*)d_ws;
  auto alloc = [&](size_t bytes) {
    char* r = p;
    p += (bytes + 255) & ~(size_t)255;
    return r;
  };
  const size_t NB2 = (size_t)N_NODES * DIM * 2;
  const size_t NB4 = (size_t)N_NODES * DIM * 4;
  ushort* xbb = (ushort*)alloc(NB2);
  ushort* qb = (ushort*)alloc(NB2);
  ushort* kvh = (ushort*)alloc(NB2 * 2);  // head-major [8][N][32]
  ushort* xrb = (ushort*)alloc(NB2);
  float* aout = (float*)alloc(NB4);
  float* xf0 = (float*)alloc(NB4);
  float* xf1 = (float*)alloc(NB4);
  ushort* wt = (ushort*)alloc((size_t)13 * DIM * DIM * 2);
  int* rowptr = (int*)alloc((N_NODES + 1) * 4);
  int* degc = (int*)alloc(N_NODES * 4);
  int* blksum = (int*)alloc(64 * 4);
  int* csr_src = (int*)alloc(N_EDGES * 4);

  prep_kernel<<<PREP_TOTAL, 256, 0, stream>>>(x_in, xbb, Wq, Wk, Wv, Wsk, Wout, wt, degc);

  count_deg_kernel<<<(N_EDGES + 255) / 256, 256, 0, stream>>>(ei, degc);
  scan1_kernel<<<N_SCAN_BLKS, SCAN_BLK, 0, stream>>>(degc, rowptr, blksum);
  scan2_kernel<<<1, 64, 0, stream>>>(blksum, rowptr);
  scan3_kernel<<<N_SCAN_BLKS, SCAN_BLK, 0, stream>>>(rowptr, blksum, degc);
  scatter_kernel<<<(N_EDGES + 255) / 256, 256, 0, stream>>>(ei, rowptr, degc, csr_src);

  const int GX = (N_NODES + 127) / 128;  // 157
  const float* xres = x_in;
  float* xfbufs[NLAYER] = {xf0, xf1, xf0};
  for (int l = 0; l < NLAYER; ++l) {
    gemm_mfma_kernel<1><<<dim3(GX, 4), 256, 0, stream>>>(
        xbb, wt + (size_t)l * 4 * DIM * DIM,
        bq + (size_t)l * DIM, bk + (size_t)l * DIM, bv + (size_t)l * DIM,
        bsk + (size_t)l * DIM,
        qb, kvh, kvh, xrb, 0, 1, 2, 0);
    attn_gather_kernel<<<(N_NODES / 4) * 8, 256, 0, stream>>>(
        qb, kvh, rowptr, csr_src, aout);
    attn_epi_kernel<<<N_NODES / 4, 256, 0, stream>>>(
        aout, xrb, xres,
        Wb + (size_t)l * 3 * DIM, lng + (size_t)l * DIM, lnb + (size_t)l * DIM,
        xfbufs[l], xbb);
    xres = xfbufs[l];
  }
  gemm_mfma_kernel<0><<<dim3(GX, 1), 256, 0, stream>>>(
      xbb, wt + (size_t)12 * DIM * DIM, bout, bout, bout, bout,
      out, out, out, out, 0, 0, 0, 0);
}

// Round 7
// 207.754 us; speedup vs baseline: 1.4757x; 1.4757x over previous
//
#include <hip/hip_runtime.h>

#define N_NODES 20000
#define N_EDGES 320000
#define DIM 128
#define NLAYER 3
#define SCAN_BLK 1024
#define N_SCAN_BLKS ((N_NODES + SCAN_BLK - 1) / SCAN_BLK)  // 20
#define LDS_STRIDE 136

// prep kernel task ranges (256-thread blocks): cast_w | zero degc
#define PREP_CASTW_BLKS 208
#define PREP_ZERO_BLKS 79
#define PREP_TOTAL (PREP_CASTW_BLKS + PREP_ZERO_BLKS)

typedef __attribute__((ext_vector_type(8))) short short8;
typedef __attribute__((ext_vector_type(4))) float f32x4;

__device__ inline ushort f2bf(float f) {
  uint u = __float_as_uint(f);
  uint r = (u + 0x7fffu + ((u >> 16) & 1u)) >> 16;
  return (ushort)r;
}
__device__ inline float bf2f(ushort u) { return __uint_as_float(((uint)u) << 16); }

// ---------------- fused prep: cast_w | zero degc ----------------
__global__ __launch_bounds__(256) void prep_kernel(
    const float* __restrict__ Wq, const float* __restrict__ Wk,
    const float* __restrict__ Wv, const float* __restrict__ Ws,
    const float* __restrict__ Wo, ushort* __restrict__ wt,
    int* __restrict__ degc) {
  int b = blockIdx.x;
  int t = threadIdx.x;
  if (b < PREP_CASTW_BLKS) {
    int z = b >> 4;
    int r = b & 15;
    int k0 = (r >> 2) * 32, n0 = (r & 3) * 32;
    const float* src;
    if (z < 12) {
      int l = z >> 2, j = z & 3;
      src = (j == 0 ? Wq : j == 1 ? Wk : j == 2 ? Wv : Ws) + (size_t)l * DIM * DIM;
    } else {
      src = Wo;
    }
    __shared__ float tile[32][33];
    int tx = t & 31, ty = t >> 5;
    #pragma unroll
    for (int i = 0; i < 32; i += 8)
      tile[ty + i][tx] = src[(size_t)(k0 + ty + i) * DIM + n0 + tx];
    __syncthreads();
    ushort* dst = wt + (size_t)z * DIM * DIM;
    #pragma unroll
    for (int i = 0; i < 32; i += 8)
      dst[(size_t)(n0 + ty + i) * DIM + k0 + tx] = f2bf(tile[tx][ty + i]);
  } else {
    int i = (b - PREP_CASTW_BLKS) * 256 + t;
    if (i < N_NODES) degc[i] = 0;
  }
}

// ---------------- CSR build ----------------

__global__ void count_deg_kernel(const int* __restrict__ ei, int* __restrict__ deg) {
  int e = blockIdx.x * 256 + threadIdx.x;
  if (e < N_EDGES) atomicAdd(&deg[ei[N_EDGES + e]], 1);
}

__global__ __launch_bounds__(SCAN_BLK) void scan1_kernel(const int* __restrict__ deg,
                                                         int* __restrict__ rowptr,
                                                         int* __restrict__ blksum) {
  __shared__ int wsum[16];
  int t = threadIdx.x, lane = t & 63, w = t >> 6;
  int i = blockIdx.x * SCAN_BLK + t;
  int val = (i < N_NODES) ? deg[i] : 0;
  int s = val;
  #pragma unroll
  for (int off = 1; off < 64; off <<= 1) {
    int u = __shfl_up(s, off);
    if (lane >= off) s += u;
  }
  if (lane == 63) wsum[w] = s;
  __syncthreads();
  if (t < 16) {
    int wv = wsum[t];
    int ss = wv;
    #pragma unroll
    for (int off = 1; off < 16; off <<= 1) {
      int u = __shfl_up(ss, off);
      if (t >= off) ss += u;
    }
    wsum[t] = ss - wv;
  }
  __syncthreads();
  int excl = wsum[w] + s - val;
  if (i < N_NODES) rowptr[i] = excl;
  if (t == SCAN_BLK - 1) blksum[blockIdx.x] = excl + val;
}

__global__ void scan2_kernel(int* __restrict__ blksum, int* __restrict__ rowptr) {
  int t = threadIdx.x;  // 64
  int val = (t < N_SCAN_BLKS) ? blksum[t] : 0;
  int s = val;
  #pragma unroll
  for (int off = 1; off < 64; off <<= 1) {
    int u = __shfl_up(s, off);
    if (t >= off) s += u;
  }
  if (t < N_SCAN_BLKS) blksum[t] = s - val;
  if (t == 63) rowptr[N_NODES] = s;
}

__global__ __launch_bounds__(SCAN_BLK) void scan3_kernel(int* __restrict__ rowptr,
                                                         const int* __restrict__ blksum,
                                                         int* __restrict__ degc) {
  int i = blockIdx.x * SCAN_BLK + threadIdx.x;
  if (i < N_NODES) {
    rowptr[i] += blksum[blockIdx.x];
    degc[i] = 0;
  }
}

__global__ void scatter_kernel(const int* __restrict__ ei, const int* __restrict__ rowptr,
                               int* __restrict__ cursor, int* __restrict__ csr_src) {
  int e = blockIdx.x * 256 + threadIdx.x;
  if (e < N_EDGES) {
    int d = ei[N_EDGES + e];
    int s = ei[e];
    int pos = atomicAdd(&cursor[d], 1);
    csr_src[rowptr[d] + pos] = s;
  }
}

// ---------------- bf16 MFMA GEMM: O_j = X @ W_j + b_j ----------------
// grid (ceil(M/128), nmat), block 256 = 4 waves 2x2; wave tile 64x64.
// IN_F32: stage fp32 X with inline cast (layer 0 — kills the cast_x pass).
// Output: ushort/float at per-mat row stride (kv interleaved via base+stride).
template <int OUT_BF16, int IN_F32>
__global__ __launch_bounds__(256) void gemm_mfma_kernel(
    const void* __restrict__ Xp, const ushort* __restrict__ WT,
    const float* __restrict__ B0, const float* __restrict__ B1,
    const float* __restrict__ B2, const float* __restrict__ B3,
    void* __restrict__ O0, void* __restrict__ O1, void* __restrict__ O2,
    void* __restrict__ O3, int st0, int st1, int st2, int st3) {
  __shared__ ushort As[128 * LDS_STRIDE];
  int mat = blockIdx.y;
  const ushort* Wt = WT + (size_t)mat * DIM * DIM;
  const float* bias;
  void* O;
  int ost;
  switch (mat) {
    case 0: bias = B0; O = O0; ost = st0; break;
    case 1: bias = B1; O = O1; ost = st1; break;
    case 2: bias = B2; O = O2; ost = st2; break;
    default: bias = B3; O = O3; ost = st3; break;
  }
  int t = threadIdx.x;
  int wid = t >> 6, lane = t & 63;
  int row0 = blockIdx.x * 128;
  int wr = wid >> 1, wc = wid & 1;
  int lr = lane & 15;
  int kc8 = (lane >> 4) * 8;

  if (IN_F32) {
    const float* Xf = (const float*)Xp;
    int rowi = t >> 5;          // 8 rows per pass
    int col4 = (t & 31) * 4;    // f32 elems
    #pragma unroll
    for (int pass = 0; pass < 16; ++pass) {
      int row = pass * 8 + rowi;
      int gr = min(row0 + row, N_NODES - 1);
      float4 f = *(const float4*)(Xf + (size_t)gr * DIM + col4);
      ushort4 u;
      u.x = f2bf(f.x); u.y = f2bf(f.y); u.z = f2bf(f.z); u.w = f2bf(f.w);
      *(ushort4*)(As + row * LDS_STRIDE + col4) = u;
    }
  } else {
    const ushort* X = (const ushort*)Xp;
    int rowi = t >> 4;
    int col = (t & 15) * 8;
    #pragma unroll
    for (int pass = 0; pass < 8; ++pass) {
      int row = pass * 16 + rowi;
      int gr = min(row0 + row, N_NODES - 1);
      short8 val = *(const short8*)(X + (size_t)gr * DIM + col);
      *(short8*)(As + row * LDS_STRIDE + col) = val;
    }
  }
  __syncthreads();

  f32x4 acc[4][4];
  #pragma unroll
  for (int i = 0; i < 4; ++i)
    #pragma unroll
    for (int j = 0; j < 4; ++j) acc[i][j] = (f32x4){0.f, 0.f, 0.f, 0.f};

  #pragma unroll
  for (int ks = 0; ks < 4; ++ks) {
    short8 b[4];
    #pragma unroll
    for (int cf = 0; cf < 4; ++cf) {
      int c = wc * 64 + cf * 16 + lr;
      b[cf] = *(const short8*)(Wt + (size_t)c * DIM + ks * 32 + kc8);
    }
    #pragma unroll
    for (int rf = 0; rf < 4; ++rf) {
      int r = wr * 64 + rf * 16 + lr;
      short8 a = *(const short8*)(As + r * LDS_STRIDE + ks * 32 + kc8);
      #pragma unroll
      for (int cf = 0; cf < 4; ++cf)
        acc[rf][cf] = __builtin_amdgcn_mfma_f32_16x16x32_bf16(a, b[cf], acc[rf][cf], 0, 0, 0);
    }
  }

  // C/D layout: col = lane&15, row = (lane>>4)*4 + reg  [m89-verified]
  #pragma unroll
  for (int cf = 0; cf < 4; ++cf) {
    int c = wc * 64 + cf * 16 + lr;
    float bv = bias[c];
    #pragma unroll
    for (int rf = 0; rf < 4; ++rf) {
      #pragma unroll
      for (int reg = 0; reg < 4; ++reg) {
        int r = row0 + wr * 64 + rf * 16 + (lane >> 4) * 4 + reg;
        if (r < N_NODES) {
          float val = acc[rf][cf][reg] + bv;
          if (OUT_BF16)
            ((ushort*)O)[(size_t)r * ost + c] = f2bf(val);
          else
            ((float*)O)[(size_t)r * ost + c] = val;
        }
      }
    }
  }
}

// ---------------- fused attention + beta-skip + relu + residual + layernorm --------
// 256-thread blocks, 4 waves, one dst node per wave. lane = (e = lane>>3, h = lane&7):
// each lane does the full 16-ch dot + v-accum for its (edge,head); 8 edges in flight.
// kv interleaved: kv[node][0..127]=k, [128..255]=v. Cross-lane reduce over the 8
// e-lanes via LDS transpose (wave-private, lgkmcnt only) instead of 17x3 butterfly.
__global__ __launch_bounds__(256) void attn_fused_kernel(
    const ushort* __restrict__ q, const ushort* __restrict__ kv,
    const ushort* __restrict__ xr, const float* __restrict__ xres,
    const int* __restrict__ rowptr, const int* __restrict__ csr_src,
    const float* __restrict__ wbeta, const float* __restrict__ lng,
    const float* __restrict__ lnb, float* __restrict__ xnext,
    ushort* __restrict__ xnextb) {
  __shared__ float red[4][8][8][20];  // [wave][e][h][17 used, pad 20 for 16B align]
  int w = threadIdx.x >> 6;
  int lane = threadIdx.x & 63;
  int n = blockIdx.x * 4 + w;
  int h = lane & 7, e = lane >> 3;

  const ushort* qrow = q + (size_t)n * DIM + h * 16;
  short8 q0 = *(const short8*)qrow;
  short8 q1 = *(const short8*)(qrow + 8);
  float qf[16];
  #pragma unroll
  for (int i = 0; i < 8; ++i) {
    qf[i] = bf2f((ushort)q0[i]) * 0.25f;      // 1/sqrt(C) folded into q
    qf[8 + i] = bf2f((ushort)q1[i]) * 0.25f;
  }

  int s0 = rowptr[n];
  int deg = rowptr[n + 1] - s0;
  float acc[16];
  #pragma unroll
  for (int i = 0; i < 16; ++i) acc[i] = 0.f;
  float dsum = 0.f;

  int src_n = (deg > 0) ? csr_src[s0 + min(e, deg - 1)] : 0;
  for (int base = 0; base < deg; base += 8) {
    int idx = base + e;
    bool valid = idx < deg;
    int src = src_n;
    if (base + 8 < deg)  // prefetch next iteration's index
      src_n = csr_src[s0 + min(base + 8 + e, deg - 1)];
    const ushort* kr = kv + (size_t)src * 256 + h * 16;
    short8 ka = *(const short8*)kr;
    short8 kb2 = *(const short8*)(kr + 8);
    short8 va = *(const short8*)(kr + 128);
    short8 vb2 = *(const short8*)(kr + 136);
    float p0 = 0.f, p1 = 0.f;
    #pragma unroll
    for (int i = 0; i < 8; ++i) {
      p0 = fmaf(qf[i], bf2f((ushort)ka[i]), p0);
      p1 = fmaf(qf[8 + i], bf2f((ushort)kb2[i]), p1);
    }
    float ea = __expf(p0 + p1);
    ea = valid ? ea : 0.f;
    dsum += ea;
    #pragma unroll
    for (int i = 0; i < 8; ++i) {
      acc[i] = fmaf(ea, bf2f((ushort)va[i]), acc[i]);
      acc[8 + i] = fmaf(ea, bf2f((ushort)vb2[i]), acc[8 + i]);
    }
  }

  // ---- LDS transpose reduce over the 8 e-lanes (wave-private) ----
  {
    float* my = &red[w][e][h][0];
    *(float4*)(my + 0) = make_float4(acc[0], acc[1], acc[2], acc[3]);
    *(float4*)(my + 4) = make_float4(acc[4], acc[5], acc[6], acc[7]);
    *(float4*)(my + 8) = make_float4(acc[8], acc[9], acc[10], acc[11]);
    *(float4*)(my + 12) = make_float4(acc[12], acc[13], acc[14], acc[15]);
    my[16] = dsum;
  }
  asm volatile("s_waitcnt lgkmcnt(0)" ::: "memory");

  // epilogue: lane owns channels (2*lane, 2*lane+1)
  int c0 = lane * 2;
  int hh = lane >> 3, cc = (lane & 7) * 2;
  float o0 = 0.f, o1 = 0.f, den = 0.f;
  #pragma unroll
  for (int ee = 0; ee < 8; ++ee) {
    float2 tv = *(float2*)&red[w][ee][hh][cc];
    o0 += tv.x;
    o1 += tv.y;
    den += red[w][ee][hh][16];
  }
  float inv = 1.f / (den + 1e-16f);
  o0 *= inv;
  o1 *= inv;

  ushort2 xru = *(const ushort2*)(xr + (size_t)n * DIM + c0);
  float xr0 = bf2f(xru.x), xr1 = bf2f(xru.y);
  float wa0 = wbeta[c0] + wbeta[2 * DIM + c0];
  float wa1 = wbeta[c0 + 1] + wbeta[2 * DIM + c0 + 1];
  float wb0 = wbeta[DIM + c0] - wbeta[2 * DIM + c0];
  float wb1 = wbeta[DIM + c0 + 1] - wbeta[2 * DIM + c0 + 1];
  float bs = o0 * wa0 + o1 * wa1 + xr0 * wb0 + xr1 * wb1;
  #pragma unroll
  for (int off = 1; off < 64; off <<= 1) bs += __shfl_xor(bs, off);
  float beta = 1.f / (1.f + __expf(-bs));
  float y0 = fmaxf(beta * xr0 + (1.f - beta) * o0, 0.f);
  float y1 = fmaxf(beta * xr1 + (1.f - beta) * o1, 0.f);
  float2 rv = *(const float2*)(xres + (size_t)n * DIM + c0);
  y0 += rv.x;
  y1 += rv.y;
  float s = y0 + y1;
  #pragma unroll
  for (int off = 1; off < 64; off <<= 1) s += __shfl_xor(s, off);
  float mu = s * (1.f / 128.f);
  float d0 = y0 - mu, d1 = y1 - mu;
  float vs = d0 * d0 + d1 * d1;
  #pragma unroll
  for (int off = 1; off < 64; off <<= 1) vs += __shfl_xor(vs, off);
  float rstd = rsqrtf(vs * (1.f / 128.f) + 1e-5f);
  float2 g = *(const float2*)(lng + c0);
  float2 b = *(const float2*)(lnb + c0);
  float out0 = d0 * rstd * g.x + b.x;
  float out1 = d1 * rstd * g.y + b.y;
  *(float2*)(xnext + (size_t)n * DIM + c0) = make_float2(out0, out1);
  ushort2 ob;
  ob.x = f2bf(out0);
  ob.y = f2bf(out1);
  *(ushort2*)(xnextb + (size_t)n * DIM + c0) = ob;
}

// ---------------- launch ----------------

extern "C" void kernel_launch(void* const* d_in, const int* in_sizes, int n_in,
                              void* d_out, int out_size, void* d_ws, size_t ws_size,
                              hipStream_t stream) {
  const float* x_in = (const float*)d_in[0];
  const int* ei = (const int*)d_in[1];
  const float* Wq = (const float*)d_in[2];
  const float* bq = (const float*)d_in[3];
  const float* Wk = (const float*)d_in[4];
  const float* bk = (const float*)d_in[5];
  const float* Wv = (const float*)d_in[6];
  const float* bv = (const float*)d_in[7];
  const float* Wsk = (const float*)d_in[8];
  const float* bsk = (const float*)d_in[9];
  const float* Wb = (const float*)d_in[10];
  const float* lng = (const float*)d_in[11];
  const float* lnb = (const float*)d_in[12];
  const float* Wout = (const float*)d_in[13];
  const float* bout = (const float*)d_in[14];
  float* out = (float*)d_out;

  char* p = (char*)d_ws;
  auto alloc = [&](size_t bytes) {
    char* r = p;
    p += (bytes + 255) & ~(size_t)255;
    return r;
  };
  const size_t NB2 = (size_t)N_NODES * DIM * 2;
  const size_t NB4 = (size_t)N_NODES * DIM * 4;
  ushort* xbb = (ushort*)alloc(NB2);      // bf16 x (written by attn for layers 1,2)
  ushort* qb = (ushort*)alloc(NB2);
  ushort* kvb = (ushort*)alloc(NB2 * 2);  // interleaved [node][k:128 | v:128]
  ushort* xrb = (ushort*)alloc(NB2);
  float* xf0 = (float*)alloc(NB4);
  float* xf1 = (float*)alloc(NB4);
  ushort* wt = (ushort*)alloc((size_t)13 * DIM * DIM * 2);
  int* rowptr = (int*)alloc((N_NODES + 1) * 4);
  int* degc = (int*)alloc(N_NODES * 4);
  int* blksum = (int*)alloc(64 * 4);
  int* csr_src = (int*)alloc(N_EDGES * 4);

  // prep (cast_w | zero degc)
  prep_kernel<<<PREP_TOTAL, 256, 0, stream>>>(Wq, Wk, Wv, Wsk, Wout, wt, degc);

  // CSR by dst
  count_deg_kernel<<<(N_EDGES + 255) / 256, 256, 0, stream>>>(ei, degc);
  scan1_kernel<<<N_SCAN_BLKS, SCAN_BLK, 0, stream>>>(degc, rowptr, blksum);
  scan2_kernel<<<1, 64, 0, stream>>>(blksum, rowptr);
  scan3_kernel<<<N_SCAN_BLKS, SCAN_BLK, 0, stream>>>(rowptr, blksum, degc);
  scatter_kernel<<<(N_EDGES + 255) / 256, 256, 0, stream>>>(ei, rowptr, degc, csr_src);

  const int GX = (N_NODES + 127) / 128;  // 157
  const float* xres = x_in;
  float* xfbufs[NLAYER] = {xf0, xf1, xf0};
  for (int l = 0; l < NLAYER; ++l) {
    const void* xin_l = (l == 0) ? (const void*)x_in : (const void*)xbb;
    if (l == 0) {
      gemm_mfma_kernel<1, 1><<<dim3(GX, 4), 256, 0, stream>>>(
          xin_l, wt + (size_t)l * 4 * DIM * DIM,
          bq + (size_t)l * DIM, bk + (size_t)l * DIM, bv + (size_t)l * DIM,
          bsk + (size_t)l * DIM,
          qb, kvb, kvb + 128, xrb, DIM, 256, 256, DIM);
    } else {
      gemm_mfma_kernel<1, 0><<<dim3(GX, 4), 256, 0, stream>>>(
          xin_l, wt + (size_t)l * 4 * DIM * DIM,
          bq + (size_t)l * DIM, bk + (size_t)l * DIM, bv + (size_t)l * DIM,
          bsk + (size_t)l * DIM,
          qb, kvb, kvb + 128, xrb, DIM, 256, 256, DIM);
    }
    attn_fused_kernel<<<N_NODES / 4, 256, 0, stream>>>(
        qb, kvb, xrb, xres, rowptr, csr_src,
        Wb + (size_t)l * 3 * DIM, lng + (size_t)l * DIM, lnb + (size_t)l * DIM,
        xfbufs[l], xbb);
    xres = xfbufs[l];
  }
  gemm_mfma_kernel<0, 0><<<dim3(GX, 1), 256, 0, stream>>>(
      xbb, wt + (size_t)12 * DIM * DIM, bout, bout, bout, bout,
      out, out, out, out, DIM, DIM, DIM, DIM);
}